// Round 6
// baseline (504.614 us; speedup 1.0000x reference)
//
#include <hip/hip_runtime.h>
#include <cmath>

typedef unsigned short ushort;
typedef __bf16 bf16x8 __attribute__((ext_vector_type(8)));
typedef float f32x4 __attribute__((ext_vector_type(4)));
typedef float f32x16 __attribute__((ext_vector_type(16)));
typedef unsigned int uint4v __attribute__((ext_vector_type(4)));
typedef unsigned int u2v __attribute__((ext_vector_type(2)));
typedef unsigned short ushort4v __attribute__((ext_vector_type(4)));

#define BB 2
#define TT 2048
#define DD 2048
#define HH 16
#define LATD 512
#define RDD 64
#define HDD 128
#define BT 4096
#define LDQ 3072
#define LDK 4096
#define LD1 1088

__device__ __forceinline__ ushort f2bf(float f) {
  union { float f; unsigned u; } v; v.f = f;
  return (ushort)((v.u + 0x7fffu + ((v.u >> 16) & 1u)) >> 16);
}
__device__ __forceinline__ float bf2f(ushort u) {
  union { unsigned u; float f; } v; v.u = ((unsigned)u) << 16; return v.f;
}
__device__ __forceinline__ f32x4 f4zero() {
  f32x4 v; v[0] = 0.f; v[1] = 0.f; v[2] = 0.f; v[3] = 0.f; return v;
}
__device__ __forceinline__ unsigned pkbf(float a, float b) {
  unsigned r;
  asm("v_cvt_pk_bf16_f32 %0, %1, %2" : "=v"(r) : "v"(a), "v"(b));
  return r;  // lo16 = bf16(a), hi16 = bf16(b)
}
__device__ __forceinline__ u2v pl32(unsigned a, unsigned b) {
  return __builtin_amdgcn_permlane32_swap(a, b, false, false);
}
// value from lane^32 (hl = lane>>5)
__device__ __forceinline__ float xswap32(float v, int hl) {
  union { float f; unsigned u; } a; a.f = v;
  u2v r = pl32(a.u, a.u);
  union { unsigned u; float f; } o; o.u = hl ? r[0] : r[1];
  return o.f;
}

typedef __attribute__((address_space(1))) void g_void;
typedef __attribute__((address_space(3))) void l_void;
__device__ __forceinline__ void gld16(void* lds, const void* g) {
  __builtin_amdgcn_global_load_lds((g_void*)(unsigned long long)g, (l_void*)lds, 16, 0, 0);
}

// ---------- elementwise f32 -> bf16 ----------
__global__ void k_cvt(const float* __restrict__ in, ushort* __restrict__ out, int n4) {
  int i = blockIdx.x * 256 + threadIdx.x;
  if (i >= n4) return;
  f32x4 v = *(const f32x4*)(in + (size_t)i * 4);
  ushort4v u;
#pragma unroll
  for (int r = 0; r < 4; ++r) u[r] = f2bf(v[r]);
  *(ushort4v*)(out + (size_t)i * 4) = u;
}

// ---------- transpose weight: f32 (R x C) -> bf16 (C x R) ----------
__global__ void k_tw(const float* __restrict__ in, ushort* __restrict__ out, int R, int C) {
  __shared__ float t[32][33];
  int c0 = blockIdx.x * 32, r0 = blockIdx.y * 32;
  int tx = threadIdx.x, ty = threadIdx.y;
#pragma unroll
  for (int i = 0; i < 4; ++i)
    t[ty + i * 8][tx] = in[(size_t)(r0 + ty + i * 8) * C + c0 + tx];
  __syncthreads();
#pragma unroll
  for (int i = 0; i < 4; ++i)
    out[(size_t)(c0 + ty + i * 8) * R + r0 + tx] = f2bf(t[tx][ty + i * 8]);
}

// ---------- rope tables ----------
__global__ void k_tables(float* __restrict__ cosT, float* __restrict__ sinT) {
  int i = blockIdx.x * 256 + threadIdx.x;
  int t = i >> 5, jj = i & 31;
  float freq = exp2f(-(float)jj * (13.287712379549449f / 32.0f));
  float ang = (float)t * freq;
  float s, c;
  sincosf(ang, &s, &c);
  cosT[i] = c; sinT[i] = s;
}

// ---------- rope apply: bf16 in (strided) -> bf16 out (compact width 1<<lw) ----------
__global__ void k_rope(const ushort* __restrict__ in, int in_stride, ushort* __restrict__ out,
                       int lw, const float* __restrict__ cosT, const float* __restrict__ sinT) {
  int idx = blockIdx.x * 256 + threadIdx.x;
  int row = idx >> lw, col = idx & ((1 << lw) - 1);
  int t = row & (TT - 1);
  int j = col & 63, jj = j & 31;
  float c = cosT[t * 32 + jj], s = sinT[t * 32 + jj];
  const ushort* ip = in + (size_t)row * in_stride;
  float xv = bf2f(ip[col]);
  float xp = (j < 32) ? -bf2f(ip[col + 32]) : bf2f(ip[col - 32]);
  out[idx] = f2bf(xv * c + xp * s);
}

// ---------- per-head V transpose: kv slice (stride LDK) -> (b,h,d,t) ----------
__global__ void k_vt(const ushort* __restrict__ in, ushort* __restrict__ out) {
  __shared__ ushort tile[32][33];
  int bh = blockIdx.z, b = bh >> 4, h = bh & 15;
  int t0 = blockIdx.x * 32, d0 = blockIdx.y * 32;
  int tx = threadIdx.x, ty = threadIdx.y;
#pragma unroll
  for (int i = 0; i < 4; ++i)
    tile[ty + i * 8][tx] = in[(size_t)(b * TT + t0 + ty + i * 8) * LDK + h * HDD + d0 + tx];
  __syncthreads();
#pragma unroll
  for (int i = 0; i < 4; ++i)
    out[(size_t)(bh * HDD + d0 + ty + i * 8) * TT + t0 + tx] = tile[tx][ty + i * 8];
}

// ---------- aoT (b,h,d,t) -> ao (b,t,h*128+d) ----------
__global__ void k_ta(const ushort* __restrict__ in, ushort* __restrict__ out) {
  __shared__ ushort tile[32][33];
  int bh = blockIdx.z, b = bh >> 4, h = bh & 15;
  int t0 = blockIdx.x * 32, d0 = blockIdx.y * 32;
  int tx = threadIdx.x, ty = threadIdx.y;
#pragma unroll
  for (int i = 0; i < 4; ++i)
    tile[ty + i * 8][tx] = in[(size_t)(bh * HDD + d0 + ty + i * 8) * TT + t0 + tx];
  __syncthreads();
#pragma unroll
  for (int i = 0; i < 4; ++i)
    out[(size_t)(b * TT + t0 + ty + i * 8) * DD + h * HDD + d0 + tx] = tile[tx][ty + i * 8];
}

// ---------- GEMM (m97 structure): global_load_lds w16, linear LDS, strided A/C ----------
template <typename OutT>
__global__ __launch_bounds__(256) void k_gemm(const ushort* __restrict__ A,
                                              const ushort* __restrict__ Bt,
                                              OutT* __restrict__ C,
                                              int M, int N, int K, int lda, int ldc, float alpha) {
  __shared__ __align__(16) ushort As[128 * 64];
  __shared__ __align__(16) ushort Bs[128 * 64];
  int tid = threadIdx.x;
  int lane = tid & 63, wid = tid >> 6;
  int wm = wid >> 1, wn = wid & 1;
  int lo = lane & 15, hi = lane >> 4;
  int m0 = blockIdx.y * 128, n0 = blockIdx.x * 128;
  int lr = lane >> 3, lc = (lane & 7) * 8;
  f32x4 acc[4][4];
#pragma unroll
  for (int m = 0; m < 4; ++m)
#pragma unroll
    for (int n = 0; n < 4; ++n) acc[m][n] = f4zero();

  for (int k0 = 0; k0 < K; k0 += 64) {
    __syncthreads();
#pragma unroll
    for (int it = 0; it < 4; ++it) {
      int c = wid * 4 + it;
      int row = c * 8 + lr;
      gld16(As + c * 512, A + (size_t)(m0 + row) * lda + k0 + lc);
      gld16(Bs + c * 512, Bt + (size_t)(n0 + row) * K + k0 + lc);
    }
    __syncthreads();
#pragma unroll
    for (int kk = 0; kk < 2; ++kk) {
      bf16x8 af[4], bfr[4];
#pragma unroll
      for (int m = 0; m < 4; ++m)
        af[m] = *(const bf16x8*)(As + (wm * 64 + m * 16 + lo) * 64 + kk * 32 + hi * 8);
#pragma unroll
      for (int n = 0; n < 4; ++n)
        bfr[n] = *(const bf16x8*)(Bs + (wn * 64 + n * 16 + lo) * 64 + kk * 32 + hi * 8);
      __builtin_amdgcn_s_setprio(1);
#pragma unroll
      for (int m = 0; m < 4; ++m)
#pragma unroll
        for (int n = 0; n < 4; ++n)
          acc[m][n] = __builtin_amdgcn_mfma_f32_16x16x32_bf16(af[m], bfr[n], acc[m][n], 0, 0, 0);
      __builtin_amdgcn_s_setprio(0);
    }
  }
#pragma unroll
  for (int m = 0; m < 4; ++m)
#pragma unroll
    for (int n = 0; n < 4; ++n)
#pragma unroll
      for (int r = 0; r < 4; ++r) {
        int row = m0 + wm * 64 + m * 16 + hi * 4 + r;
        int col = n0 + wn * 64 + n * 16 + lo;
        if (col < N) {
          float v = acc[m][n][r] * alpha;
          if constexpr (sizeof(OutT) == 4) C[(size_t)row * ldc + col] = v;
          else C[(size_t)row * ldc + col] = f2bf(v);
        }
      }
}

// ---------- causal flash attention v6: 32x32 swapped-QK, lane-local softmax ----------
// v5 + (a) 3 blocks/CU, (b) permlane32_swap P-assembly (T12), (c) XCD-aware work
// permutation: all 16 pair-blocks of one (h,b) land on one XCD (K/V L2-local).
__global__ __launch_bounds__(256, 3) void k_attn(const ushort* __restrict__ qb, const ushort* __restrict__ qrb,
                                                 const ushort* __restrict__ kb, const ushort* __restrict__ krb,
                                                 const ushort* __restrict__ vt, ushort* __restrict__ aoT) {
  __shared__ __align__(16) ushort KsL[2][64 * 128];  // K rows, col16 ^= row&7
  __shared__ __align__(16) ushort KrL[2][64 * 64];   // kr rows, col16 ^= row&7
  const int tid = threadIdx.x, lane = tid & 63, w = tid >> 6;
  const int cq = lane & 31;   // q slot (0-15 = tile A, 16-31 = tile B)
  const int hl = lane >> 5;   // k-slice half
  // XCD-aware decode: hw linear id = x + 16y + 256z, XCD = id % 8.
  // combo = id & 31 fixes (h,b) -> same XCD for all 16 pr-blocks of that (h,b).
  const int lin = (int)blockIdx.x + 16 * (int)blockIdx.y + 256 * (int)blockIdx.z;
  const int combo = lin & 31;
  const int pr = lin >> 5, h = combo & 15, b = combo >> 4;
  const int tA = pr, tB = 31 - pr;
  const int nch = tB + 1;
  const int qrow = (cq < 16) ? (tA * 64 + w * 16 + cq) : (tB * 64 + w * 16 + (cq - 16));
  const int swz = (lane & 7) << 3;  // read-side XOR (ushort units)

  // Q fragments: 12 x bf16x8 (k-dim 192 in 16-slices)
  bf16x8 qf[12];
  {
    const ushort* qp = qb + (size_t)(b * TT + qrow) * LDQ + h * HDD;
#pragma unroll
    for (int f = 0; f < 8; ++f) qf[f] = *(const bf16x8*)(qp + f * 16 + hl * 8);
    const ushort* qrp = qrb + (size_t)(b * TT + qrow) * 1024 + h * RDD;
#pragma unroll
    for (int f = 0; f < 4; ++f) qf[8 + f] = *(const bf16x8*)(qrp + f * 16 + hl * 8);
  }
  f32x16 o0, o1, o2, o3;
#pragma unroll
  for (int r = 0; r < 16; ++r) { o0[r] = 0.f; o1[r] = 0.f; o2[r] = 0.f; o3[r] = 0.f; }
  float m = -__builtin_inff(), l = 0.f;

  auto stage = [&](int buf, int kb0) {
#pragma unroll
    for (int it = 0; it < 4; ++it) {
      int cb = (tid & ~63) + it * 256;  // wave-uniform base
      int c = cb + lane;
      int row = c >> 4;
      int ccg = (c & 15) ^ (row & 7);
      gld16(&KsL[buf][cb * 8], kb + (size_t)(b * TT + kb0 + row) * LDK + h * HDD + ccg * 8);
    }
#pragma unroll
    for (int it = 0; it < 2; ++it) {
      int cb = (tid & ~63) + it * 256;
      int c = cb + lane;
      int row = c >> 3;
      int ccg = (c & 7) ^ (row & 7);
      gld16(&KrL[buf][cb * 8], krb + (size_t)(b * TT + kb0 + row) * RDD + ccg * 8);
    }
  };

  stage(0, 0);
  __syncthreads();

  const ushort* vth = vt + (size_t)(b * HH + h) * HDD * TT;

  int cur = 0;
  for (int ch = 0; ch < nch; ++ch) {
    const int kb0 = ch * 64;
    if (ch + 1 < nch) stage(cur ^ 1, kb0 + 64);

    // ---- QK^T (swapped): s0/s1 = S^T[kpos][q] ----
    f32x16 s0, s1;
#pragma unroll
    for (int r = 0; r < 16; ++r) { s0[r] = 0.f; s1[r] = 0.f; }
    __builtin_amdgcn_s_setprio(1);
#pragma unroll
    for (int f = 0; f < 12; ++f) {
      const ushort* base = (f < 8) ? &KsL[cur][0] : &KrL[cur][0];
      const int stride = (f < 8) ? 128 : 64;
      const int colU = ((f < 8) ? f * 16 : (f - 8) * 16) + hl * 8;
      bf16x8 k0 = *(const bf16x8*)(base + cq * stride + (colU ^ swz));
      bf16x8 k1 = *(const bf16x8*)(base + (32 + cq) * stride + (colU ^ swz));
      s0 = __builtin_amdgcn_mfma_f32_32x32x16_bf16(k0, qf[f], s0, 0, 0, 0);
      s1 = __builtin_amdgcn_mfma_f32_32x32x16_bf16(k1, qf[f], s1, 0, 0, 0);
    }
    __builtin_amdgcn_s_setprio(0);

    // ---- mask + lane-local max ----
    float mx = -__builtin_inff();
#pragma unroll
    for (int r = 0; r < 16; ++r) {
      int kp = kb0 + (r & 3) + 8 * (r >> 2) + 4 * hl;
      if (kp > qrow) s0[r] = -__builtin_inff();
      mx = fmaxf(mx, s0[r]);
      if (kp + 32 > qrow) s1[r] = -__builtin_inff();
      mx = fmaxf(mx, s1[r]);
    }
    mx = fmaxf(mx, xswap32(mx, hl));

    // prefetch V dtile 0 (hides under softmax)
    uint4v va[4], vb2[4];
    {
      const ushort* vp = vth + (size_t)(0 * 32 + cq) * TT + kb0 + hl * 8;
      va[0] = *(const uint4v*)(vp);
      va[1] = *(const uint4v*)(vp + 16);
      va[2] = *(const uint4v*)(vp + 32);
      va[3] = *(const uint4v*)(vp + 48);
    }

    bool defer = __all(mx <= m + 8.f);  // T13
    float mnew = defer ? m : fmaxf(m, mx);
    float rs = 0.f;
#pragma unroll
    for (int r = 0; r < 16; ++r) {
      s0[r] = exp2f(s0[r] - mnew); rs += s0[r];
      s1[r] = exp2f(s1[r] - mnew); rs += s1[r];
    }
    rs += xswap32(rs, hl);
    if (!defer) {
      float al = exp2f(m - mnew);
#pragma unroll
      for (int r = 0; r < 16; ++r) { o0[r] *= al; o1[r] *= al; o2[r] *= al; o3[r] *= al; }
      l = l * al + rs;
      m = mnew;
    } else {
      l += rs;
    }

    // ---- P fragments in-register: cvt_pk + permlane32_swap (T12) ----
    bf16x8 pf0, pf1, pf2, pf3;
#define PBUILD(PF, S, RB)                                                   \
    {                                                                       \
      unsigned a2 = pkbf(S[RB + 0], S[RB + 1]);                             \
      unsigned b2 = pkbf(S[RB + 2], S[RB + 3]);                             \
      unsigned c2 = pkbf(S[RB + 4], S[RB + 5]);                             \
      unsigned d2 = pkbf(S[RB + 6], S[RB + 7]);                             \
      u2v r02 = pl32(a2, c2);                                               \
      u2v r13 = pl32(b2, d2);                                               \
      union { uint4v u; bf16x8 v; } pb_;                                    \
      pb_.u[0] = r02[0];                                                    \
      pb_.u[1] = r13[0];                                                    \
      pb_.u[2] = r02[1];                                                    \
      pb_.u[3] = r13[1];                                                    \
      PF = pb_.v;                                                           \
    }
    PBUILD(pf0, s0, 0)
    PBUILD(pf1, s0, 8)
    PBUILD(pf2, s1, 0)
    PBUILD(pf3, s1, 8)
#undef PBUILD

    // ---- PV: O^T[d][q] += V^T-frag x P-frag, 4 dtiles, pipelined V loads ----
#define VLOAD(DST, DT)                                                      \
    {                                                                       \
      const ushort* vp = vth + (size_t)((DT) * 32 + cq) * TT + kb0 + hl * 8;\
      DST[0] = *(const uint4v*)(vp);                                        \
      DST[1] = *(const uint4v*)(vp + 16);                                   \
      DST[2] = *(const uint4v*)(vp + 32);                                   \
      DST[3] = *(const uint4v*)(vp + 48);                                   \
    }
#define PVSTEP(OD, VS)                                                      \
    {                                                                       \
      union { uint4v u; bf16x8 v; } cv_;                                    \
      __builtin_amdgcn_s_setprio(1);                                        \
      cv_.u = VS[0]; OD = __builtin_amdgcn_mfma_f32_32x32x16_bf16(cv_.v, pf0, OD, 0, 0, 0); \
      cv_.u = VS[1]; OD = __builtin_amdgcn_mfma_f32_32x32x16_bf16(cv_.v, pf1, OD, 0, 0, 0); \
      cv_.u = VS[2]; OD = __builtin_amdgcn_mfma_f32_32x32x16_bf16(cv_.v, pf2, OD, 0, 0, 0); \
      cv_.u = VS[3]; OD = __builtin_amdgcn_mfma_f32_32x32x16_bf16(cv_.v, pf3, OD, 0, 0, 0); \
      __builtin_amdgcn_s_setprio(0);                                        \
    }
    VLOAD(vb2, 1)
    PVSTEP(o0, va)
    VLOAD(va, 2)
    PVSTEP(o1, vb2)
    VLOAD(vb2, 3)
    PVSTEP(o2, va)
    PVSTEP(o3, vb2)
#undef VLOAD
#undef PVSTEP

    __syncthreads();  // drains staged gld16 for buffer cur^1
    cur ^= 1;
  }

  // ---- epilogue: O^T/l -> aoT (b,h,d,t) ----
  float inv = 1.0f / l;
  const size_t obase = (size_t)(b * HH + h) * HDD;
#define OSTORE(OD, DT)                                                      \
  _Pragma("unroll")                                                         \
  for (int r = 0; r < 16; ++r) {                                            \
    int dr = (DT) * 32 + (r & 3) + 8 * (r >> 2) + 4 * hl;                   \
    aoT[(obase + dr) * TT + qrow] = f2bf(OD[r] * inv);                      \
  }
  OSTORE(o0, 0)
  OSTORE(o1, 1)
  OSTORE(o2, 2)
  OSTORE(o3, 3)
#undef OSTORE
}

extern "C" void kernel_launch(void* const* d_in, const int* in_sizes, int n_in,
                              void* d_out, int out_size, void* d_ws, size_t ws_size,
                              hipStream_t stream) {
  (void)in_sizes; (void)n_in; (void)out_size; (void)ws_size;
  const float* x    = (const float*)d_in[0];
  const float* Wqd  = (const float*)d_in[1];
  const float* Wqu  = (const float*)d_in[2];
  const float* Wqr  = (const float*)d_in[3];
  const float* Wkvd = (const float*)d_in[4];
  const float* Wku  = (const float*)d_in[5];
  const float* Wvu  = (const float*)d_in[6];
  const float* Wkr  = (const float*)d_in[7];
  const float* Wo   = (const float*)d_in[8];
  float* out = (float*)d_out;

  char* ws = (char*)d_ws;
  size_t off = 0;
  auto alloc = [&](size_t bytes) { void* p = ws + off; off += (bytes + 255) & ~(size_t)255; return p; };
  ushort* xb   = (ushort*)alloc((size_t)BT * DD * 2);
  ushort* w1T  = (ushort*)alloc((size_t)(LD1 + 64) * DD * 2);  // [Wqd|Wkvd|Wkr]^T (+pad rows)
  ushort* w2T  = (ushort*)alloc((size_t)3072 * LATD * 2);      // [Wqu|Wqr]^T
  ushort* w3T  = (ushort*)alloc((size_t)4096 * LATD * 2);      // [Wku|Wvu]^T
  ushort* woT  = (ushort*)alloc((size_t)DD * DD * 2);
  ushort* xc   = (ushort*)alloc((size_t)BT * LD1 * 2);         // [ql | ckv | kr_raw]
  ushort* qqr  = (ushort*)alloc((size_t)BT * 3072 * 2);        // [q | qr_raw] (scaled)
  ushort* kv   = (ushort*)alloc((size_t)BT * 4096 * 2);        // [k | v]
  ushort* qrB  = (ushort*)alloc((size_t)BT * 1024 * 2);
  ushort* krB  = (ushort*)alloc((size_t)BT * RDD * 2);
  ushort* vtB  = (ushort*)alloc((size_t)BT * DD * 2);
  ushort* aoB  = (ushort*)alloc((size_t)BT * DD * 2);
  float*  cosT = (float*)alloc((size_t)TT * 32 * 4);
  float*  sinT = (float*)alloc((size_t)TT * 32 * 4);
  ushort* aoT  = xb;  // alias: xb dead after G1, aoT needed after attn

  float qscale = 1.4426950408889634f / sqrtf(192.0f);  // 1/sqrt(hd+rd) * log2(e)

  k_cvt<<<BT * DD / 4 / 256, 256, 0, stream>>>(x, xb, BT * DD / 4);
  k_tw<<<dim3(LATD / 32, DD / 32), dim3(32, 8), 0, stream>>>(Wqd, w1T, DD, LATD);
  k_tw<<<dim3(LATD / 32, DD / 32), dim3(32, 8), 0, stream>>>(Wkvd, w1T + (size_t)512 * DD, DD, LATD);
  k_tw<<<dim3(RDD / 32, DD / 32), dim3(32, 8), 0, stream>>>(Wkr, w1T + (size_t)1024 * DD, DD, RDD);
  k_tw<<<dim3(DD / 32, LATD / 32), dim3(32, 8), 0, stream>>>(Wqu, w2T, LATD, DD);
  k_tw<<<dim3(1024 / 32, LATD / 32), dim3(32, 8), 0, stream>>>(Wqr, w2T + (size_t)2048 * LATD, LATD, 1024);
  k_tw<<<dim3(DD / 32, LATD / 32), dim3(32, 8), 0, stream>>>(Wku, w3T, LATD, DD);
  k_tw<<<dim3(DD / 32, LATD / 32), dim3(32, 8), 0, stream>>>(Wvu, w3T + (size_t)2048 * LATD, LATD, DD);
  k_tw<<<dim3(DD / 32, DD / 32), dim3(32, 8), 0, stream>>>(Wo, woT, DD, DD);
  k_tables<<<TT * 32 / 256, 256, 0, stream>>>(cosT, sinT);

  // G1: xc = x @ [Wqd | Wkvd | Wkr]   (M=4096, N=1088, K=2048)
  k_gemm<ushort><<<dim3(9, BT / 128), 256, 0, stream>>>(xb, w1T, xc, BT, LD1, DD, DD, LD1, 1.0f);
  // G2: qqr = ql @ [Wqu | Wqr] * qscale   (N=3072, K=512)
  k_gemm<ushort><<<dim3(24, BT / 128), 256, 0, stream>>>(xc, w2T, qqr, BT, 3072, LATD, LD1, 3072, qscale);
  // G3: kv = ckv @ [Wku | Wvu]   (N=4096, K=512)
  k_gemm<ushort><<<dim3(32, BT / 128), 256, 0, stream>>>(xc + 512, w3T, kv, BT, 4096, LATD, LD1, 4096, 1.0f);

  k_rope<<<BT * 1024 / 256, 256, 0, stream>>>(qqr + 2048, 3072, qrB, 10, cosT, sinT);
  k_rope<<<BT * RDD / 256, 256, 0, stream>>>(xc + 1024, LD1, krB, 6, cosT, sinT);
  k_vt<<<dim3(TT / 32, HDD / 32, BB * HH), dim3(32, 8), 0, stream>>>(kv + 2048, vtB);

  k_attn<<<dim3(16, HH, BB), 256, 0, stream>>>(qqr, qrB, kv, krB, vtB, aoT);
  k_ta<<<dim3(TT / 32, HDD / 32, BB * HH), dim3(32, 8), 0, stream>>>(aoT, aoB);

  // G4: out = ao @ Wo   (N=2048, K=2048)
  k_gemm<float><<<dim3(16, BT / 128), 256, 0, stream>>>(aoB, woT, out, BT, DD, DD, DD, DD, 1.0f);
}

// Round 7
// 345.314 us; speedup vs baseline: 1.4613x; 1.4613x over previous
//
#include <hip/hip_runtime.h>
#include <cmath>

typedef unsigned short ushort;
typedef __bf16 bf16x8 __attribute__((ext_vector_type(8)));
typedef float f32x4 __attribute__((ext_vector_type(4)));
typedef float f32x16 __attribute__((ext_vector_type(16)));
typedef unsigned int uint4v __attribute__((ext_vector_type(4)));
typedef unsigned int u2v __attribute__((ext_vector_type(2)));
typedef unsigned short ushort4v __attribute__((ext_vector_type(4)));

#define BB 2
#define TT 2048
#define DD 2048
#define HH 16
#define LATD 512
#define RDD 64
#define HDD 128
#define BT 4096
#define LDQ 3072
#define LDK 4096
#define LD1 1088

__device__ __forceinline__ ushort f2bf(float f) {
  union { float f; unsigned u; } v; v.f = f;
  return (ushort)((v.u + 0x7fffu + ((v.u >> 16) & 1u)) >> 16);
}
__device__ __forceinline__ float bf2f(ushort u) {
  union { unsigned u; float f; } v; v.u = ((unsigned)u) << 16; return v.f;
}
__device__ __forceinline__ f32x4 f4zero() {
  f32x4 v; v[0] = 0.f; v[1] = 0.f; v[2] = 0.f; v[3] = 0.f; return v;
}
__device__ __forceinline__ unsigned pkbf(float a, float b) {
  unsigned r;
  asm("v_cvt_pk_bf16_f32 %0, %1, %2" : "=v"(r) : "v"(a), "v"(b));
  return r;  // lo16 = bf16(a), hi16 = bf16(b)
}
__device__ __forceinline__ u2v pl32(unsigned a, unsigned b) {
  return __builtin_amdgcn_permlane32_swap(a, b, false, false);
}
// value from lane^32 (hl = lane>>5)
__device__ __forceinline__ float xswap32(float v, int hl) {
  union { float f; unsigned u; } a; a.f = v;
  u2v r = pl32(a.u, a.u);
  union { unsigned u; float f; } o; o.u = hl ? r[0] : r[1];
  return o.f;
}

typedef __attribute__((address_space(1))) void g_void;
typedef __attribute__((address_space(3))) void l_void;
__device__ __forceinline__ void gld16(void* lds, const void* g) {
  __builtin_amdgcn_global_load_lds((g_void*)(unsigned long long)g, (l_void*)lds, 16, 0, 0);
}

// ---------- elementwise f32 -> bf16 ----------
__global__ void k_cvt(const float* __restrict__ in, ushort* __restrict__ out, int n4) {
  int i = blockIdx.x * 256 + threadIdx.x;
  if (i >= n4) return;
  f32x4 v = *(const f32x4*)(in + (size_t)i * 4);
  ushort4v u;
#pragma unroll
  for (int r = 0; r < 4; ++r) u[r] = f2bf(v[r]);
  *(ushort4v*)(out + (size_t)i * 4) = u;
}

// ---------- transpose weight: f32 (R x C) -> bf16 (C x R) ----------
__global__ void k_tw(const float* __restrict__ in, ushort* __restrict__ out, int R, int C) {
  __shared__ float t[32][33];
  int c0 = blockIdx.x * 32, r0 = blockIdx.y * 32;
  int tx = threadIdx.x, ty = threadIdx.y;
#pragma unroll
  for (int i = 0; i < 4; ++i)
    t[ty + i * 8][tx] = in[(size_t)(r0 + ty + i * 8) * C + c0 + tx];
  __syncthreads();
#pragma unroll
  for (int i = 0; i < 4; ++i)
    out[(size_t)(c0 + ty + i * 8) * R + r0 + tx] = f2bf(t[tx][ty + i * 8]);
}

// ---------- rope tables ----------
__global__ void k_tables(float* __restrict__ cosT, float* __restrict__ sinT) {
  int i = blockIdx.x * 256 + threadIdx.x;
  int t = i >> 5, jj = i & 31;
  float freq = exp2f(-(float)jj * (13.287712379549449f / 32.0f));
  float ang = (float)t * freq;
  float s, c;
  sincosf(ang, &s, &c);
  cosT[i] = c; sinT[i] = s;
}

// ---------- rope apply: bf16 in (strided) -> bf16 out (compact width 1<<lw) ----------
__global__ void k_rope(const ushort* __restrict__ in, int in_stride, ushort* __restrict__ out,
                       int lw, const float* __restrict__ cosT, const float* __restrict__ sinT) {
  int idx = blockIdx.x * 256 + threadIdx.x;
  int row = idx >> lw, col = idx & ((1 << lw) - 1);
  int t = row & (TT - 1);
  int j = col & 63, jj = j & 31;
  float c = cosT[t * 32 + jj], s = sinT[t * 32 + jj];
  const ushort* ip = in + (size_t)row * in_stride;
  float xv = bf2f(ip[col]);
  float xp = (j < 32) ? -bf2f(ip[col + 32]) : bf2f(ip[col - 32]);
  out[idx] = f2bf(xv * c + xp * s);
}

// ---------- per-head V transpose: kv slice (stride LDK) -> (b,h,d,t) ----------
__global__ void k_vt(const ushort* __restrict__ in, ushort* __restrict__ out) {
  __shared__ ushort tile[32][33];
  int bh = blockIdx.z, b = bh >> 4, h = bh & 15;
  int t0 = blockIdx.x * 32, d0 = blockIdx.y * 32;
  int tx = threadIdx.x, ty = threadIdx.y;
#pragma unroll
  for (int i = 0; i < 4; ++i)
    tile[ty + i * 8][tx] = in[(size_t)(b * TT + t0 + ty + i * 8) * LDK + h * HDD + d0 + tx];
  __syncthreads();
#pragma unroll
  for (int i = 0; i < 4; ++i)
    out[(size_t)(bh * HDD + d0 + ty + i * 8) * TT + t0 + tx] = tile[tx][ty + i * 8];
}

// ---------- aoT (b,h,d,t) -> ao (b,t,h*128+d) ----------
__global__ void k_ta(const ushort* __restrict__ in, ushort* __restrict__ out) {
  __shared__ ushort tile[32][33];
  int bh = blockIdx.z, b = bh >> 4, h = bh & 15;
  int t0 = blockIdx.x * 32, d0 = blockIdx.y * 32;
  int tx = threadIdx.x, ty = threadIdx.y;
#pragma unroll
  for (int i = 0; i < 4; ++i)
    tile[ty + i * 8][tx] = in[(size_t)(bh * HDD + d0 + ty + i * 8) * TT + t0 + tx];
  __syncthreads();
#pragma unroll
  for (int i = 0; i < 4; ++i)
    out[(size_t)(b * TT + t0 + ty + i * 8) * DD + h * HDD + d0 + tx] = tile[tx][ty + i * 8];
}

// ---------- GEMM (m97 structure): global_load_lds w16, linear LDS, strided A/C ----------
template <typename OutT>
__global__ __launch_bounds__(256) void k_gemm(const ushort* __restrict__ A,
                                              const ushort* __restrict__ Bt,
                                              OutT* __restrict__ C,
                                              int M, int N, int K, int lda, int ldc, float alpha) {
  __shared__ __align__(16) ushort As[128 * 64];
  __shared__ __align__(16) ushort Bs[128 * 64];
  int tid = threadIdx.x;
  int lane = tid & 63, wid = tid >> 6;
  int wm = wid >> 1, wn = wid & 1;
  int lo = lane & 15, hi = lane >> 4;
  int m0 = blockIdx.y * 128, n0 = blockIdx.x * 128;
  int lr = lane >> 3, lc = (lane & 7) * 8;
  f32x4 acc[4][4];
#pragma unroll
  for (int m = 0; m < 4; ++m)
#pragma unroll
    for (int n = 0; n < 4; ++n) acc[m][n] = f4zero();

  for (int k0 = 0; k0 < K; k0 += 64) {
    __syncthreads();
#pragma unroll
    for (int it = 0; it < 4; ++it) {
      int c = wid * 4 + it;
      int row = c * 8 + lr;
      gld16(As + c * 512, A + (size_t)(m0 + row) * lda + k0 + lc);
      gld16(Bs + c * 512, Bt + (size_t)(n0 + row) * K + k0 + lc);
    }
    __syncthreads();
#pragma unroll
    for (int kk = 0; kk < 2; ++kk) {
      bf16x8 af[4], bfr[4];
#pragma unroll
      for (int m = 0; m < 4; ++m)
        af[m] = *(const bf16x8*)(As + (wm * 64 + m * 16 + lo) * 64 + kk * 32 + hi * 8);
#pragma unroll
      for (int n = 0; n < 4; ++n)
        bfr[n] = *(const bf16x8*)(Bs + (wn * 64 + n * 16 + lo) * 64 + kk * 32 + hi * 8);
      __builtin_amdgcn_s_setprio(1);
#pragma unroll
      for (int m = 0; m < 4; ++m)
#pragma unroll
        for (int n = 0; n < 4; ++n)
          acc[m][n] = __builtin_amdgcn_mfma_f32_16x16x32_bf16(af[m], bfr[n], acc[m][n], 0, 0, 0);
      __builtin_amdgcn_s_setprio(0);
    }
  }
#pragma unroll
  for (int m = 0; m < 4; ++m)
#pragma unroll
    for (int n = 0; n < 4; ++n)
#pragma unroll
      for (int r = 0; r < 4; ++r) {
        int row = m0 + wm * 64 + m * 16 + hi * 4 + r;
        int col = n0 + wn * 64 + n * 16 + lo;
        if (col < N) {
          float v = acc[m][n][r] * alpha;
          if constexpr (sizeof(OutT) == 4) C[(size_t)row * ldc + col] = v;
          else C[(size_t)row * ldc + col] = f2bf(v);
        }
      }
}

// ---------- causal flash attention v7 ----------
// v5 structure (launch_bounds(256,2), ~120 VGPR, no spill) + XCD-aware decode +
// permlane32 T12 + diag-only element masking (middle chunks: 2 lane-uniform
// cndmasks) + full 16-slot K swizzle (2-way LDS conflicts = free).
__global__ __launch_bounds__(256, 2) void k_attn(const ushort* __restrict__ qb, const ushort* __restrict__ qrb,
                                                 const ushort* __restrict__ kb, const ushort* __restrict__ krb,
                                                 const ushort* __restrict__ vt, ushort* __restrict__ aoT) {
  __shared__ __align__(16) ushort KsL[2][64 * 128];  // K rows: slot16 ^= row&15
  __shared__ __align__(16) ushort KrL[2][64 * 64];   // kr rows: slot16 ^= row&7
  const int tid = threadIdx.x, lane = tid & 63, w = tid >> 6;
  const int cq = lane & 31;   // q slot (0-15 = tile A, 16-31 = tile B)
  const int hl = lane >> 5;   // k-slice half
  // XCD-aware decode: hw linear id = x + 16y + 256z, XCD = id % 8.
  // combo = id & 31 fixes (h,b) -> same XCD for all 16 pr-blocks of that (h,b).
  const int lin = (int)blockIdx.x + 16 * (int)blockIdx.y + 256 * (int)blockIdx.z;
  const int combo = lin & 31;
  const int pr = lin >> 5, h = combo & 15, b = combo >> 4;
  const int tA = pr, tB = 31 - pr;
  const int nch = tB + 1;
  const int qrow = (cq < 16) ? (tA * 64 + w * 16 + cq) : (tB * 64 + w * 16 + (cq - 16));
  const int swzK = (cq & 15) << 3;  // Ks read XOR (ushort units), rows = 16 slots
  const int swzR = (cq & 7) << 3;   // Kr read XOR, rows = 8 slots

  // Q fragments: 12 x bf16x8 (k-dim 192 in 16-slices)
  bf16x8 qf[12];
  {
    const ushort* qp = qb + (size_t)(b * TT + qrow) * LDQ + h * HDD;
#pragma unroll
    for (int f = 0; f < 8; ++f) qf[f] = *(const bf16x8*)(qp + f * 16 + hl * 8);
    const ushort* qrp = qrb + (size_t)(b * TT + qrow) * 1024 + h * RDD;
#pragma unroll
    for (int f = 0; f < 4; ++f) qf[8 + f] = *(const bf16x8*)(qrp + f * 16 + hl * 8);
  }
  f32x16 o0, o1, o2, o3;
#pragma unroll
  for (int r = 0; r < 16; ++r) { o0[r] = 0.f; o1[r] = 0.f; o2[r] = 0.f; o3[r] = 0.f; }
  float m = -__builtin_inff(), l = 0.f;

  auto stage = [&](int buf, int kb0) {
#pragma unroll
    for (int it = 0; it < 4; ++it) {
      int cb = (tid & ~63) + it * 256;  // wave-uniform base
      int c = cb + lane;
      int row = c >> 4;
      int ccg = (c & 15) ^ (row & 15);
      gld16(&KsL[buf][cb * 8], kb + (size_t)(b * TT + kb0 + row) * LDK + h * HDD + ccg * 8);
    }
#pragma unroll
    for (int it = 0; it < 2; ++it) {
      int cb = (tid & ~63) + it * 256;
      int c = cb + lane;
      int row = c >> 3;
      int ccg = (c & 7) ^ (row & 7);
      gld16(&KrL[buf][cb * 8], krb + (size_t)(b * TT + kb0 + row) * RDD + ccg * 8);
    }
  };

  stage(0, 0);
  __syncthreads();

  const ushort* vth = vt + (size_t)(b * HH + h) * HDD * TT;

  int cur = 0;
  for (int ch = 0; ch < nch; ++ch) {
    const int kb0 = ch * 64;
    if (ch + 1 < nch) stage(cur ^ 1, kb0 + 64);

    // ---- QK^T (swapped): s0/s1 = S^T[kpos][q] ----
    f32x16 s0, s1;
#pragma unroll
    for (int r = 0; r < 16; ++r) { s0[r] = 0.f; s1[r] = 0.f; }
    __builtin_amdgcn_s_setprio(1);
#pragma unroll
    for (int f = 0; f < 12; ++f) {
      const ushort* base = (f < 8) ? &KsL[cur][0] : &KrL[cur][0];
      const int stride = (f < 8) ? 128 : 64;
      const int colU = ((f < 8) ? f * 16 : (f - 8) * 16) + hl * 8;
      const int sz = (f < 8) ? swzK : swzR;
      bf16x8 k0 = *(const bf16x8*)(base + cq * stride + (colU ^ sz));
      bf16x8 k1 = *(const bf16x8*)(base + (32 + cq) * stride + (colU ^ sz));
      s0 = __builtin_amdgcn_mfma_f32_32x32x16_bf16(k0, qf[f], s0, 0, 0, 0);
      s1 = __builtin_amdgcn_mfma_f32_32x32x16_bf16(k1, qf[f], s1, 0, 0, 0);
    }
    __builtin_amdgcn_s_setprio(0);

    // ---- mask + lane-local max ----
    const bool diag = (ch == tA) || (ch == tB);
    const bool deadA = (ch > tA) && (cq < 16);  // middle chunks: A half inactive
    float mx = -__builtin_inff();
    if (diag) {
#pragma unroll
      for (int r = 0; r < 16; ++r) {
        int kp = kb0 + (r & 3) + 8 * (r >> 2) + 4 * hl;
        if (kp > qrow) s0[r] = -__builtin_inff();
        mx = fmaxf(mx, s0[r]);
        if (kp + 32 > qrow) s1[r] = -__builtin_inff();
        mx = fmaxf(mx, s1[r]);
      }
    } else {
#pragma unroll
      for (int r = 0; r < 16; ++r) mx = fmaxf(fmaxf(mx, s0[r]), s1[r]);
      if (deadA) mx = -__builtin_inff();
    }
    mx = fmaxf(mx, xswap32(mx, hl));

    // prefetch V dtile 0 (hides under softmax)
    uint4v va[4], vb2[4];
    {
      const ushort* vp = vth + (size_t)(0 * 32 + cq) * TT + kb0 + hl * 8;
      va[0] = *(const uint4v*)(vp);
      va[1] = *(const uint4v*)(vp + 16);
      va[2] = *(const uint4v*)(vp + 32);
      va[3] = *(const uint4v*)(vp + 48);
    }

    bool defer = __all(mx <= m + 8.f);  // T13
    float mnew = defer ? m : fmaxf(m, mx);
    float mE = (!diag && deadA) ? __builtin_inff() : mnew;  // dead half -> P=0
    float rs = 0.f;
#pragma unroll
    for (int r = 0; r < 16; ++r) {
      s0[r] = exp2f(s0[r] - mE); rs += s0[r];
      s1[r] = exp2f(s1[r] - mE); rs += s1[r];
    }
    rs += xswap32(rs, hl);
    if (!defer) {
      float al = exp2f(m - mnew);
#pragma unroll
      for (int r = 0; r < 16; ++r) { o0[r] *= al; o1[r] *= al; o2[r] *= al; o3[r] *= al; }
      l = l * al + rs;
      m = mnew;
    } else {
      l += rs;
    }

    // ---- P fragments in-register: cvt_pk + permlane32_swap (T12) ----
    bf16x8 pf0, pf1, pf2, pf3;
#define PBUILD(PF, S, RB)                                                   \
    {                                                                       \
      unsigned a2 = pkbf(S[RB + 0], S[RB + 1]);                             \
      unsigned b2 = pkbf(S[RB + 2], S[RB + 3]);                             \
      unsigned c2 = pkbf(S[RB + 4], S[RB + 5]);                             \
      unsigned d2 = pkbf(S[RB + 6], S[RB + 7]);                             \
      u2v r02 = pl32(a2, c2);                                               \
      u2v r13 = pl32(b2, d2);                                               \
      union { uint4v u; bf16x8 v; } pb_;                                    \
      pb_.u[0] = r02[0];                                                    \
      pb_.u[1] = r13[0];                                                    \
      pb_.u[2] = r02[1];                                                    \
      pb_.u[3] = r13[1];                                                    \
      PF = pb_.v;                                                           \
    }
    PBUILD(pf0, s0, 0)
    PBUILD(pf1, s0, 8)
    PBUILD(pf2, s1, 0)
    PBUILD(pf3, s1, 8)
#undef PBUILD

    // ---- PV: O^T[d][q] += V^T-frag x P-frag, 4 dtiles, pipelined V loads ----
#define VLOAD(DST, DT)                                                      \
    {                                                                       \
      const ushort* vp = vth + (size_t)((DT) * 32 + cq) * TT + kb0 + hl * 8;\
      DST[0] = *(const uint4v*)(vp);                                        \
      DST[1] = *(const uint4v*)(vp + 16);                                   \
      DST[2] = *(const uint4v*)(vp + 32);                                   \
      DST[3] = *(const uint4v*)(vp + 48);                                   \
    }
#define PVSTEP(OD, VS)                                                      \
    {                                                                       \
      union { uint4v u; bf16x8 v; } cv_;                                    \
      __builtin_amdgcn_s_setprio(1);                                        \
      cv_.u = VS[0]; OD = __builtin_amdgcn_mfma_f32_32x32x16_bf16(cv_.v, pf0, OD, 0, 0, 0); \
      cv_.u = VS[1]; OD = __builtin_amdgcn_mfma_f32_32x32x16_bf16(cv_.v, pf1, OD, 0, 0, 0); \
      cv_.u = VS[2]; OD = __builtin_amdgcn_mfma_f32_32x32x16_bf16(cv_.v, pf2, OD, 0, 0, 0); \
      cv_.u = VS[3]; OD = __builtin_amdgcn_mfma_f32_32x32x16_bf16(cv_.v, pf3, OD, 0, 0, 0); \
      __builtin_amdgcn_s_setprio(0);                                        \
    }
    VLOAD(vb2, 1)
    PVSTEP(o0, va)
    VLOAD(va, 2)
    PVSTEP(o1, vb2)
    VLOAD(vb2, 3)
    PVSTEP(o2, va)
    PVSTEP(o3, vb2)
#undef VLOAD
#undef PVSTEP

    __syncthreads();  // drains staged gld16 for buffer cur^1
    cur ^= 1;
  }

  // ---- epilogue: O^T/l -> aoT (b,h,d,t) ----
  float inv = 1.0f / l;
  const size_t obase = (size_t)(b * HH + h) * HDD;
#define OSTORE(OD, DT)                                                      \
  _Pragma("unroll")                                                         \
  for (int r = 0; r < 16; ++r) {                                            \
    int dr = (DT) * 32 + (r & 3) + 8 * (r >> 2) + 4 * hl;                   \
    aoT[(obase + dr) * TT + qrow] = f2bf(OD[r] * inv);                      \
  }
  OSTORE(o0, 0)
  OSTORE(o1, 1)
  OSTORE(o2, 2)
  OSTORE(o3, 3)
#undef OSTORE
}

extern "C" void kernel_launch(void* const* d_in, const int* in_sizes, int n_in,
                              void* d_out, int out_size, void* d_ws, size_t ws_size,
                              hipStream_t stream) {
  (void)in_sizes; (void)n_in; (void)out_size; (void)ws_size;
  const float* x    = (const float*)d_in[0];
  const float* Wqd  = (const float*)d_in[1];
  const float* Wqu  = (const float*)d_in[2];
  const float* Wqr  = (const float*)d_in[3];
  const float* Wkvd = (const float*)d_in[4];
  const float* Wku  = (const float*)d_in[5];
  const float* Wvu  = (const float*)d_in[6];
  const float* Wkr  = (const float*)d_in[7];
  const float* Wo   = (const float*)d_in[8];
  float* out = (float*)d_out;

  char* ws = (char*)d_ws;
  size_t off = 0;
  auto alloc = [&](size_t bytes) { void* p = ws + off; off += (bytes + 255) & ~(size_t)255; return p; };
  ushort* xb   = (ushort*)alloc((size_t)BT * DD * 2);
  ushort* w1T  = (ushort*)alloc((size_t)(LD1 + 64) * DD * 2);  // [Wqd|Wkvd|Wkr]^T (+pad rows)
  ushort* w2T  = (ushort*)alloc((size_t)3072 * LATD * 2);      // [Wqu|Wqr]^T
  ushort* w3T  = (ushort*)alloc((size_t)4096 * LATD * 2);      // [Wku|Wvu]^T
  ushort* woT  = (ushort*)alloc((size_t)DD * DD * 2);
  ushort* xc   = (ushort*)alloc((size_t)BT * LD1 * 2);         // [ql | ckv | kr_raw]
  ushort* qqr  = (ushort*)alloc((size_t)BT * 3072 * 2);        // [q | qr_raw] (scaled)
  ushort* kv   = (ushort*)alloc((size_t)BT * 4096 * 2);        // [k | v]
  ushort* qrB  = (ushort*)alloc((size_t)BT * 1024 * 2);
  ushort* krB  = (ushort*)alloc((size_t)BT * RDD * 2);
  ushort* vtB  = (ushort*)alloc((size_t)BT * DD * 2);
  ushort* aoB  = (ushort*)alloc((size_t)BT * DD * 2);
  float*  cosT = (float*)alloc((size_t)TT * 32 * 4);
  float*  sinT = (float*)alloc((size_t)TT * 32 * 4);
  ushort* aoT  = xb;  // alias: xb dead after G1, aoT needed after attn

  float qscale = 1.4426950408889634f / sqrtf(192.0f);  // 1/sqrt(hd+rd) * log2(e)

  k_cvt<<<BT * DD / 4 / 256, 256, 0, stream>>>(x, xb, BT * DD / 4);
  k_tw<<<dim3(LATD / 32, DD / 32), dim3(32, 8), 0, stream>>>(Wqd, w1T, DD, LATD);
  k_tw<<<dim3(LATD / 32, DD / 32), dim3(32, 8), 0, stream>>>(Wkvd, w1T + (size_t)512 * DD, DD, LATD);
  k_tw<<<dim3(RDD / 32, DD / 32), dim3(32, 8), 0, stream>>>(Wkr, w1T + (size_t)1024 * DD, DD, RDD);
  k_tw<<<dim3(DD / 32, LATD / 32), dim3(32, 8), 0, stream>>>(Wqu, w2T, LATD, DD);
  k_tw<<<dim3(1024 / 32, LATD / 32), dim3(32, 8), 0, stream>>>(Wqr, w2T + (size_t)2048 * LATD, LATD, 1024);
  k_tw<<<dim3(DD / 32, LATD / 32), dim3(32, 8), 0, stream>>>(Wku, w3T, LATD, DD);
  k_tw<<<dim3(DD / 32, LATD / 32), dim3(32, 8), 0, stream>>>(Wvu, w3T + (size_t)2048 * LATD, LATD, DD);
  k_tw<<<dim3(DD / 32, DD / 32), dim3(32, 8), 0, stream>>>(Wo, woT, DD, DD);
  k_tables<<<TT * 32 / 256, 256, 0, stream>>>(cosT, sinT);

  // G1: xc = x @ [Wqd | Wkvd | Wkr]   (M=4096, N=1088, K=2048)
  k_gemm<ushort><<<dim3(9, BT / 128), 256, 0, stream>>>(xb, w1T, xc, BT, LD1, DD, DD, LD1, 1.0f);
  // G2: qqr = ql @ [Wqu | Wqr] * qscale   (N=3072, K=512)
  k_gemm<ushort><<<dim3(24, BT / 128), 256, 0, stream>>>(xc, w2T, qqr, BT, 3072, LATD, LD1, 3072, qscale);
  // G3: kv = ckv @ [Wku | Wvu]   (N=4096, K=512)
  k_gemm<ushort><<<dim3(32, BT / 128), 256, 0, stream>>>(xc + 512, w3T, kv, BT, 4096, LATD, LD1, 4096, 1.0f);

  k_rope<<<BT * 1024 / 256, 256, 0, stream>>>(qqr + 2048, 3072, qrB, 10, cosT, sinT);
  k_rope<<<BT * RDD / 256, 256, 0, stream>>>(xc + 1024, LD1, krB, 6, cosT, sinT);
  k_vt<<<dim3(TT / 32, HDD / 32, BB * HH), dim3(32, 8), 0, stream>>>(kv + 2048, vtB);

  k_attn<<<dim3(16, HH, BB), 256, 0, stream>>>(qqr, qrB, kv, krB, vtB, aoT);
  k_ta<<<dim3(TT / 32, HDD / 32, BB * HH), dim3(32, 8), 0, stream>>>(aoT, aoB);

  // G4: out = ao @ Wo   (N=2048, K=2048)
  k_gemm<float><<<dim3(16, BT / 128), 256, 0, stream>>>(aoB, woT, out, BT, DD, DD, DD, DD, 1.0f);
}